// Round 3
// baseline (93.154 us; speedup 1.0000x reference)
//
#include <hip/hip_runtime.h>
#include <hip/hip_fp16.h>

#define OUT_UNITS 128
#define ROWS_PER_BLOCK 8   // 512 threads = 8 waves, one row per wave

// native clang vector types — __builtin_nontemporal_* requires these
// (HIP_vector_type float4 is a class and is rejected).
typedef float  fx4 __attribute__((ext_vector_type(4)));

// ---------------- Kernel 0: fused prep -------------------------------------
// job A (i < n4):  w fp32 -> fp16 into workspace (float4 -> 4 halves)
// job B (i < nnz): CSR row pointers from sorted COO rows
// Round 16: streaming reads (w4, rows) are non-temporal so they don't
// displace the wh table in L2; wh itself is written normally (we WANT it
// L2-resident for the spmm gather phase).
__global__ void prep(const fx4* __restrict__ w4, uint2* __restrict__ wh, int n4,
                     const int* __restrict__ rows, int* __restrict__ row_start,
                     int nnz, int n_rows) {
    int i = blockIdx.x * blockDim.x + threadIdx.x;
    if (i < n4) {
        fx4 f = __builtin_nontemporal_load(&w4[i]);
        __half2 h01 = __floats2half2_rn(f.x, f.y);
        __half2 h23 = __floats2half2_rn(f.z, f.w);
        wh[i] = make_uint2(*(unsigned*)&h01, *(unsigned*)&h23);
    }
    if (i < nnz) {
        int cur = __builtin_nontemporal_load(&rows[i]);
        if (i == 0) {
            for (int r = 0; r <= cur; ++r) row_start[r] = 0;
        } else {
            int prev = __builtin_nontemporal_load(&rows[i - 1]);
            for (int r = prev + 1; r <= cur; ++r) row_start[r] = i;
        }
        if (i == nnz - 1) {
            for (int r = cur + 1; r <= n_rows; ++r) row_start[r] = nnz;
        }
    }
}

// ---------------- Kernel 1: 8 waves/block, one row per wave ------------------
// Round-13 structure (proven 86.5 us): fp16 w, quarter-wave split (16 lanes x
// 16B cover one 256B row, one dwordx4 serves 4 nnz), 2-stage register
// pipeline (8 x 1KB gathers in flight), 512-thread blocks @ (512,8).
// Round-14 (LDS-ring staging) tied with this => gather path is
// throughput-walled, not staging/MLP-limited.
// Round 16 single change: cache-policy. The cols/vals stream (8 MB single-use)
// and the out writes (8 MB write-allocate) churn the 4 MB per-XCD L2 and
// evict the 2 MB wh gather table, pushing gather misses from L2 latency to
// L3 latency (MSHR-limited rate is proportional to 1/latency). Mark stream
// loads and out stores non-temporal ('nt': no L2 displacement); gather loads
// stay normal so wh remains the only L2-resident working set.
__global__ __launch_bounds__(512, 8)
void spmm_row_wave(const float* __restrict__ vals,
                   const __half* __restrict__ wh,
                   const int* __restrict__ cols,
                   const int* __restrict__ row_start,
                   float* __restrict__ out,
                   int n_rows) {
    __shared__ int2 cvbuf[ROWS_PER_BLOCK][64];

    const int wave = __builtin_amdgcn_readfirstlane((int)(threadIdx.x >> 6));
    const int lane = threadIdx.x & 63;
    const int r    = blockIdx.x * ROWS_PER_BLOCK + wave;
    if (r >= n_rows) return;

    const int start   = row_start[r];
    const int end     = row_start[r + 1];
    const int quarter = lane >> 4;   // which nnz of the quad
    const int sub     = lane & 15;   // 16 lanes x 8 halves = 128 cols
    const char* __restrict__ whb = (const char*)wh;
    const int loff = sub << 4;       // sub*16 bytes
    int2* cv = cvbuf[wave];

    float4 accA = make_float4(0.f, 0.f, 0.f, 0.f);  // cols sub*8 + 0..3
    float4 accB = make_float4(0.f, 0.f, 0.f, 0.f);  // cols sub*8 + 4..7

    for (int base = start; base < end; base += 64) {
        const int navail = min(64, end - base);
        // stage (c, v): pad lanes get (valid col, v=0); nt loads — the
        // cols/vals stream must not evict wh from L2.
        const int idx = base + min(lane, navail - 1);
        int   c_l = __builtin_nontemporal_load(&cols[idx]);
        float v_f = __builtin_nontemporal_load(&vals[idx]);
        float v_l = (lane < navail) ? v_f : 0.f;
        cv[lane] = make_int2(c_l, __float_as_int(v_l));
        // same-wave LDS: program-ordered, no barrier

        const int nquad  = (navail + 3) >> 2;
        const int nquad4 = (nquad + 3) & ~3;   // 4..16, multiple of 4

        // ---- prologue: stage A = quads [0,4) ----
        int2  pA[4];
        uint4 qA[4];
#pragma unroll
        for (int j = 0; j < 4; ++j) pA[j] = cv[4 * j + quarter];
#pragma unroll
        for (int j = 0; j < 4; ++j)
            qA[j] = *(const uint4*)(whb + (((size_t)(unsigned)pA[j].x) << 8) + loff);

        for (int t = 4; t < nquad4; t += 4) {
            // ---- issue stage B before consuming A ----
            int2  pB[4];
            uint4 qB[4];
#pragma unroll
            for (int j = 0; j < 4; ++j) pB[j] = cv[4 * (t + j) + quarter];
#pragma unroll
            for (int j = 0; j < 4; ++j)
                qB[j] = *(const uint4*)(whb + (((size_t)(unsigned)pB[j].x) << 8) + loff);
            // ---- consume stage A (waits vmcnt(4): B stays in flight) ----
#pragma unroll
            for (int j = 0; j < 4; ++j) {
                float v = __int_as_float(pA[j].y);
                const __half2* h = (const __half2*)&qA[j];
                float2 f0 = __half22float2(h[0]);
                float2 f1 = __half22float2(h[1]);
                float2 f2 = __half22float2(h[2]);
                float2 f3 = __half22float2(h[3]);
                accA.x = fmaf(v, f0.x, accA.x); accA.y = fmaf(v, f0.y, accA.y);
                accA.z = fmaf(v, f1.x, accA.z); accA.w = fmaf(v, f1.y, accA.w);
                accB.x = fmaf(v, f2.x, accB.x); accB.y = fmaf(v, f2.y, accB.y);
                accB.z = fmaf(v, f3.x, accB.z); accB.w = fmaf(v, f3.y, accB.w);
            }
            // ---- rotate B -> A ----
#pragma unroll
            for (int j = 0; j < 4; ++j) { pA[j] = pB[j]; qA[j] = qB[j]; }
        }

        // ---- epilogue: consume final stage ----
#pragma unroll
        for (int j = 0; j < 4; ++j) {
            float v = __int_as_float(pA[j].y);
            const __half2* h = (const __half2*)&qA[j];
            float2 f0 = __half22float2(h[0]);
            float2 f1 = __half22float2(h[1]);
            float2 f2 = __half22float2(h[2]);
            float2 f3 = __half22float2(h[3]);
            accA.x = fmaf(v, f0.x, accA.x); accA.y = fmaf(v, f0.y, accA.y);
            accA.z = fmaf(v, f1.x, accA.z); accA.w = fmaf(v, f1.y, accA.w);
            accB.x = fmaf(v, f2.x, accB.x); accB.y = fmaf(v, f2.y, accB.y);
            accB.z = fmaf(v, f3.x, accB.z); accB.w = fmaf(v, f3.y, accB.w);
        }
    }

    // fold the 4 quarters (disjoint nnz subsets)
#pragma unroll
    for (int d = 16; d <= 32; d <<= 1) {
        accA.x += __shfl_xor(accA.x, d); accA.y += __shfl_xor(accA.y, d);
        accA.z += __shfl_xor(accA.z, d); accA.w += __shfl_xor(accA.w, d);
        accB.x += __shfl_xor(accB.x, d); accB.y += __shfl_xor(accB.y, d);
        accB.z += __shfl_xor(accB.z, d); accB.w += __shfl_xor(accB.w, d);
    }

    if (quarter == 0) {
        // nt stores: out is write-once, never re-read — keep it out of L2
        fx4* o = (fx4*)(out + (size_t)r * OUT_UNITS + sub * 8);
        fx4 a; a.x = accA.x; a.y = accA.y; a.z = accA.z; a.w = accA.w;
        fx4 b; b.x = accB.x; b.y = accB.y; b.z = accB.z; b.w = accB.w;
        __builtin_nontemporal_store(a, &o[0]);
        __builtin_nontemporal_store(b, &o[1]);
    }
}

extern "C" void kernel_launch(void* const* d_in, const int* in_sizes, int n_in,
                              void* d_out, int out_size, void* d_ws, size_t ws_size,
                              hipStream_t stream) {
    const float* vals = (const float*)d_in[0];
    const float* w    = (const float*)d_in[1];
    const int*   rows = (const int*)d_in[2];
    const int*   cols = (const int*)d_in[3];
    float* out = (float*)d_out;

    const int nnz    = in_sizes[0];
    const int n_rows = out_size / OUT_UNITS;  // 16384
    const int w_n    = in_sizes[1];           // 8192*128 = 1048576
    const int n4     = w_n / 4;

    // ws layout: [0, 64KB+4) row_start ; [128KB, 128KB+2MB) w fp16
    int*    row_start = (int*)d_ws;
    __half* wh        = (__half*)((char*)d_ws + (128 << 10));

    const int prep_threads = (nnz > n4) ? nnz : n4;
    prep<<<(prep_threads + 255) / 256, 256, 0, stream>>>(
        (const fx4*)w, (uint2*)wh, n4, rows, row_start, nnz, n_rows);
    spmm_row_wave<<<(n_rows + ROWS_PER_BLOCK - 1) / ROWS_PER_BLOCK, 512, 0, stream>>>(
        vals, wh, cols, row_start, out, n_rows);
}